// Round 8
// baseline (81.038 us; speedup 1.0000x reference)
//
#include <hip/hip_runtime.h>

#define BD 4096   // rows
#define CD 256    // codes
#define DD 128    // dim
#define RB 16     // rows per block -> grid 256 = 1 block/CU (LDS-resident codebook)
#define TB 1024   // threads = 16 waves = 4 waves/SIMD
#define SF 132    // padded LDS row stride in floats (33 quads -> even bank spread)

// Lessons kept: no 2nd __launch_bounds__ arg (R4 spills); no register-carried
// prefetch across staging (R5 spills); load->ds_write immediately (R2/R6 clean).
// R7 lesson: x-broadcasts must NOT ride the LDS pipe -> dot-form + scalar loads.
__global__ __launch_bounds__(TB) void rq_fused(
    const float* __restrict__ x,
    const float* __restrict__ pq,
    const float* __restrict__ codes,
    float* __restrict__ out)   // [quantized BD*DD | indices BD | loss 1]
{
    __shared__ float code_s[CD * SF];          // 135168 B padded codebook
    __shared__ float cn2_s[CD];                // ||c||^2 per code
    __shared__ float csum_s[CD];               // sum(c) per code
    __shared__ float row_c[RB], row_s[RB], row_invn[RB], row_k1[RB], row_k2[RB];
    __shared__ int   row_idx[RB];
    __shared__ float red_v[RB * 4];            // [row][code-quarter]
    __shared__ int   red_i[RB * 4];
    __shared__ float loss_s[RB];

    const int tid  = threadIdx.x;
    const int wv   = tid >> 6;     // 0..15
    const int lane = tid & 63;
    const int row0 = blockIdx.x * RB;
    const float INV_SQRT_D = 0.088388347648318447f;  // 1/sqrt(128)

    // ---- stage full codebook to LDS: 8192 float4, 8 per thread, batch x4 ----
    {
        const float4* src = (const float4*)codes;
        #pragma unroll
        for (int k = 0; k < 8; k += 4) {
            const float4 t0 = src[(k + 0) * TB + tid];
            const float4 t1 = src[(k + 1) * TB + tid];
            const float4 t2 = src[(k + 2) * TB + tid];
            const float4 t3 = src[(k + 3) * TB + tid];
            int f;
            f = (k + 0) * TB + tid; *(float4*)(code_s + (f >> 5) * SF + (f & 31) * 4) = t0;
            f = (k + 1) * TB + tid; *(float4*)(code_s + (f >> 5) * SF + (f & 31) * 4) = t1;
            f = (k + 2) * TB + tid; *(float4*)(code_s + (f >> 5) * SF + (f & 31) * 4) = t2;
            f = (k + 3) * TB + tid; *(float4*)(code_s + (f >> 5) * SF + (f & 31) * 4) = t3;
        }
    }

    // ---------- Phase A: per-row rotation scalars (wave wv = row wv) ----------
    {
        const int r = wv;
        const size_t grow = (size_t)(row0 + r);
        const float2 xv = ((const float2*)(x  + grow * DD))[lane];
        const float2 pv = ((const float2*)(pq + grow * DD))[lane];
        float s0 = pv.x * pv.x + pv.y * pv.y;   // ||pq||^2
        float s1 = pv.x + pv.y;                 // sum pq
        float s2 = xv.x + xv.y;                 // sum x
        float s3 = pv.x * xv.x + pv.y * xv.y;   // pq . x
        #pragma unroll
        for (int m = 32; m > 0; m >>= 1) {
            s0 += __shfl_xor(s0, m);
            s1 += __shfl_xor(s1, m);
            s2 += __shfl_xor(s2, m);
            s3 += __shfl_xor(s3, m);
        }
        const float invn = 1.0f / fmaxf(sqrtf(s0), 1e-6f);  // u = pq * invn
        const float b = s2 * INV_SQRT_D;                    // v.x
        const float a = s3 * invn;                          // u.x
        const float c = s1 * invn * INV_SQRT_D;             // u.v
        const float s = 1.0f / (1.0f + c + 1e-6f);
        // xc = x + au*u + av*v
        const float au = -b + s * (c * b - a);
        const float av =  a + s * (c * a - b);
        if (lane == 0) {
            row_c[r] = c; row_s[r] = s; row_invn[r] = invn;
            // argmin score: f(c) = ||c||^2 - 2 x.c - k1*(pq.c) - k2*sum(c)
            row_k1[r] = 2.0f * au * invn;
            row_k2[r] = 2.0f * av * INV_SQRT_D;
        }
    }
    __syncthreads();   // code_s + row scalars ready

    // ---- per-code ||c||^2 and sum(c): waves 0..3, thread = code ----
    if (tid < CD) {
        const float* cp = code_s + tid * SF;
        float n2 = 0.f, sm = 0.f;
        #pragma unroll 8
        for (int i = 0; i < 32; ++i) {
            const float4 q = *(const float4*)(cp + i * 4);
            n2 = fmaf(q.x, q.x, n2); n2 = fmaf(q.y, q.y, n2);
            n2 = fmaf(q.z, q.z, n2); n2 = fmaf(q.w, q.w, n2);
            sm += q.x + q.y + q.z + q.w;
        }
        cn2_s[tid] = n2; csum_s[tid] = sm;
    }
    __syncthreads();

    // ---------- Phase B: dot-form scores (codes via LDS, x/pq via scalar loads) ----
    // wave -> 4 rows x 64 codes; thread -> 1 code x 4 rows, full D
    const int rg = wv & 3;                     // rows rg*4 .. rg*4+3
    const int cq = wv >> 2;                    // codes cq*64 + lane
    const int ci = cq * 64 + lane;
    const float cn2 = cn2_s[ci];
    const float csm = csum_s[ci];
    const int r0 = rg * 4;
    const float k10 = row_k1[r0 + 0], k20 = row_k2[r0 + 0];
    const float k11 = row_k1[r0 + 1], k21 = row_k2[r0 + 1];
    const float k12 = row_k1[r0 + 2], k22 = row_k2[r0 + 2];
    const float k13 = row_k1[r0 + 3], k23 = row_k2[r0 + 3];
    // wave-uniform row bases -> scalar (SMEM) loads for x/pq broadcasts
    const int grbase = __builtin_amdgcn_readfirstlane(row0 + r0);
    const float* xb = x  + (size_t)grbase * DD;
    const float* pb = pq + (size_t)grbase * DD;
    const float* cp = code_s + ci * SF;        // quad idx ci*33+i -> (lane+i)&7 group: even
    float ax0 = 0.f, ax1 = 0.f, ax2 = 0.f, ax3 = 0.f;
    float ap0 = 0.f, ap1 = 0.f, ap2 = 0.f, ap3 = 0.f;

    #pragma unroll 2
    for (int i = 0; i < 32; ++i) {
        const float4 cv = *(const float4*)(cp + i * 4);   // LDS, lane-distributed
        const float4 x0 = *(const float4*)(xb + 0 * DD + i * 4);  // uniform -> s_load
        const float4 x1 = *(const float4*)(xb + 1 * DD + i * 4);
        const float4 x2 = *(const float4*)(xb + 2 * DD + i * 4);
        const float4 x3 = *(const float4*)(xb + 3 * DD + i * 4);
        const float4 p0 = *(const float4*)(pb + 0 * DD + i * 4);
        const float4 p1 = *(const float4*)(pb + 1 * DD + i * 4);
        const float4 p2 = *(const float4*)(pb + 2 * DD + i * 4);
        const float4 p3 = *(const float4*)(pb + 3 * DD + i * 4);
        ax0 = fmaf(cv.x, x0.x, ax0); ax0 = fmaf(cv.y, x0.y, ax0);
        ax0 = fmaf(cv.z, x0.z, ax0); ax0 = fmaf(cv.w, x0.w, ax0);
        ap0 = fmaf(cv.x, p0.x, ap0); ap0 = fmaf(cv.y, p0.y, ap0);
        ap0 = fmaf(cv.z, p0.z, ap0); ap0 = fmaf(cv.w, p0.w, ap0);
        ax1 = fmaf(cv.x, x1.x, ax1); ax1 = fmaf(cv.y, x1.y, ax1);
        ax1 = fmaf(cv.z, x1.z, ax1); ax1 = fmaf(cv.w, x1.w, ax1);
        ap1 = fmaf(cv.x, p1.x, ap1); ap1 = fmaf(cv.y, p1.y, ap1);
        ap1 = fmaf(cv.z, p1.z, ap1); ap1 = fmaf(cv.w, p1.w, ap1);
        ax2 = fmaf(cv.x, x2.x, ax2); ax2 = fmaf(cv.y, x2.y, ax2);
        ax2 = fmaf(cv.z, x2.z, ax2); ax2 = fmaf(cv.w, x2.w, ax2);
        ap2 = fmaf(cv.x, p2.x, ap2); ap2 = fmaf(cv.y, p2.y, ap2);
        ap2 = fmaf(cv.z, p2.z, ap2); ap2 = fmaf(cv.w, p2.w, ap2);
        ax3 = fmaf(cv.x, x3.x, ax3); ax3 = fmaf(cv.y, x3.y, ax3);
        ax3 = fmaf(cv.z, x3.z, ax3); ax3 = fmaf(cv.w, x3.w, ax3);
        ap3 = fmaf(cv.x, p3.x, ap3); ap3 = fmaf(cv.y, p3.y, ap3);
        ap3 = fmaf(cv.z, p3.z, ap3); ap3 = fmaf(cv.w, p3.w, ap3);
    }

    // scores (per row; lower = closer). Constant-per-row terms omitted.
    float bv[4]; int bi[4];
    bv[0] = cn2 - 2.0f * ax0 - k10 * ap0 - k20 * csm;
    bv[1] = cn2 - 2.0f * ax1 - k11 * ap1 - k21 * csm;
    bv[2] = cn2 - 2.0f * ax2 - k12 * ap2 - k22 * csm;
    bv[3] = cn2 - 2.0f * ax3 - k13 * ap3 - k23 * csm;
    bi[0] = ci; bi[1] = ci; bi[2] = ci; bi[3] = ci;
    #pragma unroll
    for (int m = 1; m < 64; m <<= 1) {
        #pragma unroll
        for (int rr = 0; rr < 4; ++rr) {
            const float ov = __shfl_xor(bv[rr], m);
            const int   oi = __shfl_xor(bi[rr], m);
            if (ov < bv[rr] || (ov == bv[rr] && oi < bi[rr])) { bv[rr] = ov; bi[rr] = oi; }
        }
    }
    if (lane == 0) {
        #pragma unroll
        for (int rr = 0; rr < 4; ++rr) {
            red_v[(r0 + rr) * 4 + cq] = bv[rr];
            red_i[(r0 + rr) * 4 + cq] = bi[rr];
        }
    }
    __syncthreads();
    if (tid < RB) {   // merge 4 code-quarters per row (ascending cq; ties -> lower idx)
        float v0 = red_v[tid * 4]; int i0 = red_i[tid * 4];
        #pragma unroll
        for (int k = 1; k < 4; ++k) {
            const float ov = red_v[tid * 4 + k];
            const int   oi = red_i[tid * 4 + k];
            if (ov < v0 || (ov == v0 && oi < i0)) { v0 = ov; i0 = oi; }
        }
        row_idx[tid] = i0;
        out[(size_t)BD * DD + row0 + tid] = (float)i0;
    }
    __syncthreads();

    // ---------- Phase C: quantized = R * codes[idx] (rank-2), + loss ----------
    {
        const int r = wv;
        const int qi = row_idx[r];
        const float invn = row_invn[r];
        const float c = row_c[r];
        const float s = row_s[r];
        const size_t grow = (size_t)(row0 + r);
        const float2 q = ((const float2*)(code_s + qi * SF))[lane];
        const float2 p = ((const float2*)(pq + grow * DD))[lane];
        float pd = p.x * q.x + p.y * q.y;
        float ws = q.x + q.y;
        #pragma unroll
        for (int m = 32; m > 0; m >>= 1) {
            pd += __shfl_xor(pd, m);
            ws += __shfl_xor(ws, m);
        }
        const float pp = pd * invn;          // u . q
        const float w  = ws * INV_SQRT_D;    // v . q
        const float bu  =  w + s * (c * w - pp);
        const float bvv = -pp + s * (c * pp - w);
        float2 o;
        o.x = q.x + bu * (p.x * invn) + bvv * INV_SQRT_D;
        o.y = q.y + bu * (p.y * invn) + bvv * INV_SQRT_D;
        ((float2*)(out + grow * DD))[lane] = o;

        const float2 xv = ((const float2*)(x + grow * DD))[lane];
        float dx = xv.x - o.x;
        float ls = dx * dx;
        dx = xv.y - o.y;
        ls = fmaf(dx, dx, ls);
        #pragma unroll
        for (int m = 32; m > 0; m >>= 1) ls += __shfl_xor(ls, m);
        if (lane == 0) loss_s[r] = ls;
    }
    __syncthreads();
    if (tid == 0) {
        float tot = 0.f;
        #pragma unroll
        for (int r = 0; r < RB; ++r) tot += loss_s[r];
        // loss = loss_commit + 0.25*loss_codebook = 1.25 * mean_b ||x - q||^2
        atomicAdd(out + (size_t)BD * DD + BD, tot * (1.25f / (float)BD));
    }
}

extern "C" void kernel_launch(void* const* d_in, const int* in_sizes, int n_in,
                              void* d_out, int out_size, void* d_ws, size_t ws_size,
                              hipStream_t stream) {
    const float* xin   = (const float*)d_in[0];
    const float* prevq = (const float*)d_in[1];
    const float* codes = (const float*)d_in[2];
    float* out = (float*)d_out;
    // zero the loss accumulator slot (harness poisons d_out with 0xAA)
    hipMemsetAsync((void*)(out + (size_t)BD * DD + BD), 0, sizeof(float), stream);
    rq_fused<<<BD / RB, TB, 0, stream>>>(xin, prevq, codes, out);
}

// Round 9
// 74.450 us; speedup vs baseline: 1.0885x; 1.0885x over previous
//
#include <hip/hip_runtime.h>

#define BD 4096   // rows
#define CD 256    // codes
#define DD 128    // dim
#define RB 16     // rows per block -> grid 256 = 1 block/CU (LDS-resident codebook)
#define TB 1024   // threads = 16 waves = 4 waves/SIMD
#define SF 132    // padded code row stride in floats (33 quads -> even bank spread)

// Lessons kept: no 2nd __launch_bounds__ arg (R4: VGPR=32 + 72MB spills); no
// register-carried prefetch across staging (R5: spills); load->ds_write
// immediately (R2/R6 clean). R8 lesson: uniform x/pq loads do NOT become
// s_load -> keep broadcasts on LDS. This round: score = ||c||^2 - 2*xc.c
// (1 fma/pair), thread tile 2 codes x 4 rows, d-split by 2 with LDS merge.
__global__ __launch_bounds__(TB) void rq_fused(
    const float* __restrict__ x,
    const float* __restrict__ pq,
    const float* __restrict__ codes,
    float* __restrict__ out)   // [quantized BD*DD | indices BD | loss 1]
{
    // Manual LDS pool: mbuf aliases code_s (code_s is dead after Phase B;
    // Phase C reloads its code row from global).
    __shared__ __align__(16) char pool[CD * SF * 4        // code_s  135168 B
                                       + RB * DD * 4      // xc_s      8192 B
                                       + CD * 4           // cn2_s     1024 B
                                       + RB * 4 * 4       // row_c/s/invn + pad
                                       + RB * 4           // row_idx
                                       + RB * 2 * 8       // red_v/red_i
                                       + RB * 4];         // loss_s
    float* code_s = (float*)pool;                          // [256][SF]
    float* mbuf   = (float*)pool;                          // alias: [8][64][8] = 16 KB
    float* xc_s   = (float*)(pool + CD * SF * 4);          // [16][128]
    float* cn2_s  = xc_s + RB * DD;                        // [256]
    float* row_c  = cn2_s + CD;                            // [16]
    float* row_s  = row_c + RB;
    float* row_invn = row_s + RB;
    float* row_pad  = row_invn + RB;  (void)row_pad;
    int*   row_idx  = (int*)(row_invn + 2 * RB);
    float* red_v    = (float*)(row_idx + RB);              // [16][2]
    int*   red_i    = (int*)(red_v + RB * 2);              // [16][2]
    float* loss_s   = (float*)(red_i + RB * 2);            // [16]

    const int tid  = threadIdx.x;
    const int wv   = tid >> 6;     // 0..15
    const int lane = tid & 63;
    const int row0 = blockIdx.x * RB;
    const float INV_SQRT_D = 0.088388347648318447f;  // 1/sqrt(128)

    // ---- stage full codebook to LDS: 8192 float4, 8 per thread, batch x4 ----
    {
        const float4* src = (const float4*)codes;
        #pragma unroll
        for (int k = 0; k < 8; k += 4) {
            const float4 t0 = src[(k + 0) * TB + tid];
            const float4 t1 = src[(k + 1) * TB + tid];
            const float4 t2 = src[(k + 2) * TB + tid];
            const float4 t3 = src[(k + 3) * TB + tid];
            int f;
            f = (k + 0) * TB + tid; *(float4*)(code_s + (f >> 5) * SF + (f & 31) * 4) = t0;
            f = (k + 1) * TB + tid; *(float4*)(code_s + (f >> 5) * SF + (f & 31) * 4) = t1;
            f = (k + 2) * TB + tid; *(float4*)(code_s + (f >> 5) * SF + (f & 31) * 4) = t2;
            f = (k + 3) * TB + tid; *(float4*)(code_s + (f >> 5) * SF + (f & 31) * 4) = t3;
        }
    }

    // ---------- Phase A: per-row rotation, xc -> LDS (wave wv = row wv) ------
    {
        const int r = wv;
        const size_t grow = (size_t)(row0 + r);
        const float2 xv = ((const float2*)(x  + grow * DD))[lane];
        const float2 pv = ((const float2*)(pq + grow * DD))[lane];
        float s0 = pv.x * pv.x + pv.y * pv.y;   // ||pq||^2
        float s1 = pv.x + pv.y;                 // sum pq
        float s2 = xv.x + xv.y;                 // sum x
        float s3 = pv.x * xv.x + pv.y * xv.y;   // pq . x
        #pragma unroll
        for (int m = 32; m > 0; m >>= 1) {
            s0 += __shfl_xor(s0, m);
            s1 += __shfl_xor(s1, m);
            s2 += __shfl_xor(s2, m);
            s3 += __shfl_xor(s3, m);
        }
        const float invn = 1.0f / fmaxf(sqrtf(s0), 1e-6f);  // u = pq * invn
        const float b = s2 * INV_SQRT_D;                    // v.x
        const float a = s3 * invn;                          // u.x
        const float c = s1 * invn * INV_SQRT_D;             // u.v
        const float s = 1.0f / (1.0f + c + 1e-6f);
        // xc = R^T x = x + au*u + av*v
        const float au = -b + s * (c * b - a);
        const float av =  a + s * (c * a - b);
        float2 o;
        o.x = xv.x + au * (pv.x * invn) + av * INV_SQRT_D;
        o.y = xv.y + au * (pv.y * invn) + av * INV_SQRT_D;
        ((float2*)(xc_s + r * DD))[lane] = o;
        if (lane == 0) { row_c[r] = c; row_s[r] = s; row_invn[r] = invn; }
    }
    __syncthreads();   // code_s + xc_s ready

    // ---- cn2: ||c||^2 per code; thread -> (code tid>>2, quarter tid&3) ----
    {
        const int c = tid >> 2, q = tid & 3;
        const float* cp = code_s + c * SF + q * 32;
        float n2 = 0.f;
        #pragma unroll
        for (int i = 0; i < 8; ++i) {
            const float4 v = *(const float4*)(cp + i * 4);
            n2 = fmaf(v.x, v.x, n2); n2 = fmaf(v.y, v.y, n2);
            n2 = fmaf(v.z, v.z, n2); n2 = fmaf(v.w, v.w, n2);
        }
        n2 += __shfl_xor(n2, 1);
        n2 += __shfl_xor(n2, 2);
        if (q == 0) cn2_s[c] = n2;
    }
    __syncthreads();

    // ---------- Phase B: dots, thread = 2 codes x 4 rows x half-D -----------
    // wave -> wgrp (rows rg*4.., codes ch*128 + {lane, lane+64}), half = d-split
    const int wgrp = wv & 7, half = wv >> 3;
    const int rg = wgrp & 3, ch = wgrp >> 2;
    const float* cb = code_s + (ch * 128 + lane) * SF + half * 64;
    const float* xb = xc_s + (rg * 4) * DD + half * 64;
    float a0 = 0.f, a1 = 0.f, a2 = 0.f, a3 = 0.f;
    float a4 = 0.f, a5 = 0.f, a6 = 0.f, a7 = 0.f;

    #pragma unroll 4
    for (int i = 0; i < 16; ++i) {
        const float4 c0 = *(const float4*)(cb + i * 4);            // spread
        const float4 c1 = *(const float4*)(cb + 64 * SF + i * 4);  // spread
        const float4 x0 = *(const float4*)(xb + 0 * DD + i * 4);   // broadcast
        const float4 x1 = *(const float4*)(xb + 1 * DD + i * 4);
        const float4 x2 = *(const float4*)(xb + 2 * DD + i * 4);
        const float4 x3 = *(const float4*)(xb + 3 * DD + i * 4);
        a0 = fmaf(c0.x, x0.x, a0); a0 = fmaf(c0.y, x0.y, a0);
        a0 = fmaf(c0.z, x0.z, a0); a0 = fmaf(c0.w, x0.w, a0);
        a1 = fmaf(c1.x, x0.x, a1); a1 = fmaf(c1.y, x0.y, a1);
        a1 = fmaf(c1.z, x0.z, a1); a1 = fmaf(c1.w, x0.w, a1);
        a2 = fmaf(c0.x, x1.x, a2); a2 = fmaf(c0.y, x1.y, a2);
        a2 = fmaf(c0.z, x1.z, a2); a2 = fmaf(c0.w, x1.w, a2);
        a3 = fmaf(c1.x, x1.x, a3); a3 = fmaf(c1.y, x1.y, a3);
        a3 = fmaf(c1.z, x1.z, a3); a3 = fmaf(c1.w, x1.w, a3);
        a4 = fmaf(c0.x, x2.x, a4); a4 = fmaf(c0.y, x2.y, a4);
        a4 = fmaf(c0.z, x2.z, a4); a4 = fmaf(c0.w, x2.w, a4);
        a5 = fmaf(c1.x, x2.x, a5); a5 = fmaf(c1.y, x2.y, a5);
        a5 = fmaf(c1.z, x2.z, a5); a5 = fmaf(c1.w, x2.w, a5);
        a6 = fmaf(c0.x, x3.x, a6); a6 = fmaf(c0.y, x3.y, a6);
        a6 = fmaf(c0.z, x3.z, a6); a6 = fmaf(c0.w, x3.w, a6);
        a7 = fmaf(c1.x, x3.x, a7); a7 = fmaf(c1.y, x3.y, a7);
        a7 = fmaf(c1.z, x3.z, a7); a7 = fmaf(c1.w, x3.w, a7);
    }

    __syncthreads();   // all code_s reads done -> mbuf alias is safe
    if (half == 1) {   // upper d-half: publish partial dots
        float* mb = mbuf + ((size_t)wgrp * 64 + lane) * 8;
        float4 v;
        v.x = a0; v.y = a1; v.z = a2; v.w = a3; *(float4*)(mb)     = v;
        v.x = a4; v.y = a5; v.z = a6; v.w = a7; *(float4*)(mb + 4) = v;
    }
    __syncthreads();
    if (half == 0) {   // lower d-half: merge, score, argmin
        const float* mb = mbuf + ((size_t)wgrp * 64 + lane) * 8;
        const float4 m0 = *(const float4*)(mb);
        const float4 m1 = *(const float4*)(mb + 4);
        a0 += m0.x; a1 += m0.y; a2 += m0.z; a3 += m0.w;
        a4 += m1.x; a5 += m1.y; a6 += m1.z; a7 += m1.w;
        const int c0i = ch * 128 + lane;
        const int c1i = c0i + 64;
        const float cn20 = cn2_s[c0i];
        const float cn21 = cn2_s[c1i];
        // score = ||c||^2 - 2*xc.c  (per row; constant-per-row terms dropped)
        float bv[4]; int bi[4];
        {
            const float s00 = fmaf(-2.f, a0, cn20), s01 = fmaf(-2.f, a1, cn21);
            const float s10 = fmaf(-2.f, a2, cn20), s11 = fmaf(-2.f, a3, cn21);
            const float s20 = fmaf(-2.f, a4, cn20), s21 = fmaf(-2.f, a5, cn21);
            const float s30 = fmaf(-2.f, a6, cn20), s31 = fmaf(-2.f, a7, cn21);
            // c0i < c1i, so ties keep c0i (first-min)
            if (s01 < s00) { bv[0] = s01; bi[0] = c1i; } else { bv[0] = s00; bi[0] = c0i; }
            if (s11 < s10) { bv[1] = s11; bi[1] = c1i; } else { bv[1] = s10; bi[1] = c0i; }
            if (s21 < s20) { bv[2] = s21; bi[2] = c1i; } else { bv[2] = s20; bi[2] = c0i; }
            if (s31 < s30) { bv[3] = s31; bi[3] = c1i; } else { bv[3] = s30; bi[3] = c0i; }
        }
        #pragma unroll
        for (int m = 1; m < 64; m <<= 1) {
            #pragma unroll
            for (int rr = 0; rr < 4; ++rr) {
                const float ov = __shfl_xor(bv[rr], m);
                const int   oi = __shfl_xor(bi[rr], m);
                if (ov < bv[rr] || (ov == bv[rr] && oi < bi[rr])) { bv[rr] = ov; bi[rr] = oi; }
            }
        }
        if (lane == 0) {
            #pragma unroll
            for (int rr = 0; rr < 4; ++rr) {
                red_v[(rg * 4 + rr) * 2 + ch] = bv[rr];
                red_i[(rg * 4 + rr) * 2 + ch] = bi[rr];
            }
        }
    }
    __syncthreads();
    if (tid < RB) {   // merge 2 code-halves per row (ch ascending; ties -> lower idx)
        float v0 = red_v[tid * 2]; int i0 = red_i[tid * 2];
        const float v1 = red_v[tid * 2 + 1]; const int i1 = red_i[tid * 2 + 1];
        if (v1 < v0 || (v1 == v0 && i1 < i0)) { v0 = v1; i0 = i1; }
        row_idx[tid] = i0;
        out[(size_t)BD * DD + row0 + tid] = (float)i0;
    }
    __syncthreads();

    // ---------- Phase C: quantized = R * codes[idx] (rank-2), + loss --------
    // wave wv = row wv; code row reloaded from GLOBAL (code_s is clobbered).
    {
        const int r = wv;
        const int qi = row_idx[r];
        const float invn = row_invn[r];
        const float c = row_c[r];
        const float s = row_s[r];
        const size_t grow = (size_t)(row0 + r);
        const float2 q = ((const float2*)(codes + (size_t)qi * DD))[lane];
        const float2 p = ((const float2*)(pq + grow * DD))[lane];
        float pd = p.x * q.x + p.y * q.y;
        float ws = q.x + q.y;
        #pragma unroll
        for (int m = 32; m > 0; m >>= 1) {
            pd += __shfl_xor(pd, m);
            ws += __shfl_xor(ws, m);
        }
        const float pp = pd * invn;          // u . q
        const float w  = ws * INV_SQRT_D;    // v . q
        // R q = q + u*(w + s(cw - p)) + v*(-p + s(cp - w))
        const float bu  =  w + s * (c * w - pp);
        const float bvv = -pp + s * (c * pp - w);
        float2 o;
        o.x = q.x + bu * (p.x * invn) + bvv * INV_SQRT_D;
        o.y = q.y + bu * (p.y * invn) + bvv * INV_SQRT_D;
        ((float2*)(out + grow * DD))[lane] = o;

        const float2 xv = ((const float2*)(x + grow * DD))[lane];
        float dx = xv.x - o.x;
        float ls = dx * dx;
        dx = xv.y - o.y;
        ls = fmaf(dx, dx, ls);
        #pragma unroll
        for (int m = 32; m > 0; m >>= 1) ls += __shfl_xor(ls, m);
        if (lane == 0) loss_s[r] = ls;
    }
    __syncthreads();
    if (tid == 0) {
        float tot = 0.f;
        #pragma unroll
        for (int r = 0; r < RB; ++r) tot += loss_s[r];
        // loss = loss_commit + 0.25*loss_codebook = 1.25 * mean_b ||x - q||^2
        atomicAdd(out + (size_t)BD * DD + BD, tot * (1.25f / (float)BD));
    }
}

extern "C" void kernel_launch(void* const* d_in, const int* in_sizes, int n_in,
                              void* d_out, int out_size, void* d_ws, size_t ws_size,
                              hipStream_t stream) {
    const float* xin   = (const float*)d_in[0];
    const float* prevq = (const float*)d_in[1];
    const float* codes = (const float*)d_in[2];
    float* out = (float*)d_out;
    // zero the loss accumulator slot (harness poisons d_out with 0xAA)
    hipMemsetAsync((void*)(out + (size_t)BD * DD + BD), 0, sizeof(float), stream);
    rq_fused<<<BD / RB, TB, 0, stream>>>(xin, prevq, codes, out);
}